// Round 3
// baseline (528.350 us; speedup 1.0000x reference)
//
#include <hip/hip_runtime.h>
#include <hip/hip_bf16.h>
#include <stdint.h>

// ---------------------------------------------------------------------------
// AstrocyteMemoryModule r3: 4 launches.
//  L1 prep: all converts + W^T + combined bias + barrier reset
//  L2 Wc = Wi@W (batched 1024^3, BK=64)
//  L3 kh/vhT big GEMM (XCD-swizzled, BK=64) + qh fused as 16 thin blocks
//  L4 tail: flash-attn partials -> combine -> ms -> g1 -> gate -> h1 -> out
//           one kernel, 128 co-resident blocks, manual grid barrier
// ---------------------------------------------------------------------------

typedef __bf16 bf16;
typedef __bf16 bf16x4 __attribute__((ext_vector_type(4)));
typedef __bf16 bf16x8 __attribute__((ext_vector_type(8)));
typedef float f32x4 __attribute__((ext_vector_type(4)));

#define D_ 1024
#define M_ 8192
#define B_ 64
#define H_ 16

static __device__ __forceinline__ void gload16(const void* g, void* l) {
  __builtin_amdgcn_global_load_lds(
      (const __attribute__((address_space(1))) void*)g,
      (__attribute__((address_space(3))) void*)l, 16, 0, 0);
}

static __device__ __forceinline__ f32x4 mfma16(bf16x8 a, bf16x8 b, f32x4 c) {
  return __builtin_amdgcn_mfma_f32_16x16x32_bf16(a, b, c, 0, 0, 0);
}

// ---------------- thin GEMM (M=64): C = A @ B^T, reg-prefetched -------------
// Caller pre-offsets Bm/C/bias/aux by the 64-col tile base. KLEN compile-time
// -> full unroll, double-buffered frag registers (no per-iter vmcnt(0) wall).
// EPI: 0=none, 1=relu, 2=sigmoid(val)*aux.
template <int U, int EPI, int KLEN, typename OutT>
__device__ __forceinline__ void thin_gemm(
    const bf16* __restrict__ A, int lda,
    const bf16* __restrict__ Bm, int ldb,
    OutT* __restrict__ C, int ldc,
    const float* __restrict__ bias, float scale,
    const bf16* __restrict__ aux, int ldaux) {
  const int tid = threadIdx.x, lane = tid & 63, w = tid >> 6;
  const int rl = lane & 15, qq = lane >> 4;
  const bf16* pa = A + (int64_t)(w * 16 + rl) * lda + qq * 8;
  const bf16* pb[4];
  pb[0] = Bm + (int64_t)rl * ldb + qq * 8;
  pb[1] = pb[0] + (int64_t)16 * ldb;
  pb[2] = pb[0] + (int64_t)32 * ldb;
  pb[3] = pb[0] + (int64_t)48 * ldb;
  f32x4 acc[4] = {};
  bf16x8 av[2][U], bv[2][U][4];
#pragma unroll
  for (int u = 0; u < U; u++) {
    av[0][u] = *(const bf16x8*)(pa + u * 32);
#pragma unroll
    for (int j = 0; j < 4; j++)
      bv[0][u][j] = *(const bf16x8*)(pb[j] + u * 32);
  }
  constexpr int NI = KLEN / (32 * U);
#pragma unroll
  for (int it = 0; it < NI; it++) {
    const int cur = it & 1, nxt = cur ^ 1;
    if (it + 1 < NI) {
      int k = (it + 1) * 32 * U;
#pragma unroll
      for (int u = 0; u < U; u++) {
        av[nxt][u] = *(const bf16x8*)(pa + k + u * 32);
#pragma unroll
        for (int j = 0; j < 4; j++)
          bv[nxt][u][j] = *(const bf16x8*)(pb[j] + k + u * 32);
      }
    }
#pragma unroll
    for (int u = 0; u < U; u++)
#pragma unroll
      for (int j = 0; j < 4; j++)
        acc[j] = mfma16(av[cur][u], bv[cur][u][j], acc[j]);
  }
#pragma unroll
  for (int j = 0; j < 4; j++) {
    int gn = j * 16 + rl;
    float bb = bias ? bias[gn] : 0.0f;
#pragma unroll
    for (int r = 0; r < 4; r++) {
      int gm = w * 16 + qq * 4 + r;
      float val = (acc[j][r] + bb) * scale;
      if constexpr (EPI == 1) val = fmaxf(val, 0.0f);
      if constexpr (EPI == 2) {
        float g = 1.0f / (1.0f + __expf(-val));
        val = g * (float)aux[(int64_t)gm * ldaux + gn];
      }
      C[(int64_t)gm * ldc + gn] = (OutT)val;
    }
  }
}

// ------------------------------ prep (L1) ----------------------------------
// sections: [0,29824) converts, [29824,32896) W-transpose, [32896,33664) bias
struct CvtD { const float* src; bf16* dst; int end; int shift; int stride; };
struct PrepArgs {
  CvtD d[10];
  const float *Wq, *Wk, *Wv, *inw, *inb, *bq, *bk, *bv;
  bf16* WT;
  float* bc;
  unsigned* bar;
};

__global__ __launch_bounds__(256) void prep_kernel(PrepArgs a) {
  const int bx = blockIdx.x, tid = threadIdx.x;
  if (bx == 0 && tid == 0) *a.bar = 0u;
  if (bx < 29824) {
    int g = bx * 256 + tid;
    CvtD dd = a.d[9];
    int begin = a.d[8].end;
#pragma unroll
    for (int t = 8; t >= 0; t--)
      if (g < a.d[t].end) { dd = a.d[t]; begin = t ? a.d[t - 1].end : 0; }
    int i = (g - begin) * 4;
    float4 v = *(const float4*)(dd.src + i);
    int r = i >> dd.shift;
    int c = i - (r << dd.shift);
    bf16x4 o = { (bf16)v.x, (bf16)v.y, (bf16)v.z, (bf16)v.w };
    *(bf16x4*)(dd.dst + (int64_t)r * dd.stride + c) = o;
  } else if (bx < 32896) {
    int t = bx - 29824;
    int z = t >> 10, rem = t & 1023;
    const float* src = z == 0 ? a.Wq : z == 1 ? a.Wk : a.Wv;
    bf16* out = a.WT + (int64_t)z * D_ * D_;
    __shared__ bf16 tile[32][33];
    int tx = tid & 31, ty = tid >> 5;
    int r0 = (rem >> 5) * 32, c0 = (rem & 31) * 32;
#pragma unroll
    for (int i = 0; i < 32; i += 8)
      tile[ty + i][tx] = (bf16)src[(int64_t)(r0 + ty + i) * D_ + c0 + tx];
    __syncthreads();
#pragma unroll
    for (int i = 0; i < 32; i += 8)
      out[(int64_t)(c0 + ty + i) * D_ + r0 + tx] = tile[tx][ty + i];
  } else {
    // bc[z*D+n] = dot(inw[z*D+n], b_z) + inb[z*D+n]; one wave per n
    int t = bx - 32896;
    int w = tid >> 6, lane = tid & 63;
    int ng = t * 4 + w;                    // global n in [0, 3072)
    int z = ng >> 10, n = ng & 1023;
    const float* Wi = a.inw + (int64_t)ng * D_;
    const float* b = z == 0 ? a.bq : z == 1 ? a.bk : a.bv;
    float acc = 0.f;
#pragma unroll
    for (int l = 0; l < D_; l += 64) acc += Wi[l + lane] * b[l + lane];
#pragma unroll
    for (int m = 32; m; m >>= 1) acc += __shfl_xor(acc, m, 64);
    if (lane == 0) a.bc[ng] = acc + a.inb[ng];
    (void)n;
  }
}

// ------------------------- big GEMM: C = A @ B^T (BK=64) -------------------
// 128x128 tile, 4 waves. MODE 0: 3D grid, row-major C. MODE 1: flat grid,
// XCD swizzle; z==0 -> row-major C (kh), z==1 -> transposed Ct (vhT);
// blocks >= 1024 run the fused qh thin path.
template <int MODE>
__global__ __launch_bounds__(256) void gemm_big(
    const bf16* __restrict__ A, int lda, int64_t sA,
    const bf16* __restrict__ Bm, int ldb, int64_t sB,
    bf16* __restrict__ C, int ldc, bf16* __restrict__ Ct,
    const float* __restrict__ bias, int64_t sbias, int K,
    const bf16* __restrict__ qA, const bf16* __restrict__ qB,
    bf16* __restrict__ qC, const float* __restrict__ qbias) {
  int m0, n0, z;
  if (MODE == 0) {
    z = blockIdx.z; m0 = blockIdx.y * 128; n0 = blockIdx.x * 128;
  } else {
    if ((int)blockIdx.x >= 1024) {   // fused qh: 16 thin blocks
      int n0q = ((int)blockIdx.x - 1024) * 64;
      thin_gemm<2, 0, 1024, bf16>(qA, 2 * D_, qB + (int64_t)n0q * D_, D_,
                                  qC + n0q, D_, qbias + n0q, 0.125f,
                                  nullptr, 0);
      return;
    }
    int lin = blockIdx.x, xcd = lin & 7, slot = lin >> 3;
    z = slot >> 6;
    int r = slot & 63;
    m0 = (xcd * 8 + (r >> 3)) * 128;   // XCD owns an M-band: A-tile reused 8x
    n0 = (r & 7) * 128;
  }
  A += (int64_t)z * sA; Bm += (int64_t)z * sB;
  if (bias) bias += (int64_t)z * sbias;
  __shared__ alignas(16) bf16 As[128 * 64];
  __shared__ alignas(16) bf16 Bs[128 * 64];
  const int tid = threadIdx.x, lane = tid & 63, w = tid >> 6;
  const int wm = (w & 1) * 64, wn = (w >> 1) * 64;
  const int rl = lane & 15, qq = lane >> 4;
  f32x4 acc[4][4] = {};

  const bf16 *gA[4], *gB[4];
  bf16 *lA[4], *lB[4];
#pragma unroll
  for (int it = 0; it < 4; it++) {
    int cc = it * 256 + w * 64 + lane;
    int r = cc >> 3, qp = cc & 7, q = qp ^ (r & 7);
    gA[it] = A + (int64_t)(m0 + r) * lda + q * 8;
    gB[it] = Bm + (int64_t)(n0 + r) * ldb + q * 8;
    lA[it] = As + (it * 256 + w * 64) * 8;   // wave-uniform base
    lB[it] = Bs + (it * 256 + w * 64) * 8;
  }
  for (int k0 = 0; k0 < K; k0 += 64) {
    __syncthreads();
#pragma unroll
    for (int it = 0; it < 4; it++) {
      gload16(gA[it] + k0, lA[it]);
      gload16(gB[it] + k0, lB[it]);
    }
    __syncthreads();
#pragma unroll
    for (int kk = 0; kk < 2; kk++) {
      bf16x8 af[4], bb[4];
#pragma unroll
      for (int i = 0; i < 4; i++) {
        int ar = wm + i * 16 + rl;
        af[i] = *(const bf16x8*)(As + ar * 64 + (((kk * 4 + qq) ^ (ar & 7)) * 8));
      }
#pragma unroll
      for (int j = 0; j < 4; j++) {
        int br = wn + j * 16 + rl;
        bb[j] = *(const bf16x8*)(Bs + br * 64 + (((kk * 4 + qq) ^ (br & 7)) * 8));
      }
#pragma unroll
      for (int i = 0; i < 4; i++)
#pragma unroll
        for (int j = 0; j < 4; j++)
          acc[i][j] = mfma16(af[i], bb[j], acc[i][j]);
    }
  }
  if (MODE == 1 && z == 1) {
#pragma unroll
    for (int j = 0; j < 4; j++) {
      int gn = n0 + wn + j * 16 + rl;
      float bb = bias ? bias[gn] : 0.0f;
#pragma unroll
      for (int i = 0; i < 4; i++) {
        int gm0 = m0 + wm + i * 16 + qq * 4;
        f32x4 a = acc[i][j];
        bf16x4 o = { (bf16)(a[0] + bb), (bf16)(a[1] + bb),
                     (bf16)(a[2] + bb), (bf16)(a[3] + bb) };
        *(bf16x4*)(Ct + (int64_t)gn * M_ + gm0) = o;
      }
    }
  } else {
#pragma unroll
    for (int j = 0; j < 4; j++) {
      int gn = n0 + wn + j * 16 + rl;
      float bb = bias ? bias[gn] : 0.0f;
#pragma unroll
      for (int i = 0; i < 4; i++) {
        int gm0 = m0 + wm + i * 16 + qq * 4;
#pragma unroll
        for (int r = 0; r < 4; r++)
          C[(int64_t)(gm0 + r) * ldc + gn] = (bf16)(acc[i][j][r] + bb);
      }
    }
  }
}

// ------------------------------ tail (L4) ----------------------------------
struct TailArgs {
  const bf16 *qh, *kh, *vhT;
  float *opart, *ml;
  bf16 *ctx;
  const bf16 *outwb, *gW1b, *gW2b, *iW1b, *iW2b;
  const float *outb, *gb1, *gb2, *ib1, *ib2;
  bf16 *xms, *xgm, *g1, *h1;
  float* out;
  unsigned* bar;
};

static __device__ __forceinline__ void grid_sync(unsigned* bar, unsigned target) {
  __syncthreads();
  if (threadIdx.x == 0) {
    __threadfence();
    atomicAdd(bar, 1u);
    while (__hip_atomic_load(bar, __ATOMIC_RELAXED, __HIP_MEMORY_SCOPE_AGENT) <
           target)
      __builtin_amdgcn_s_sleep(2);
    __threadfence();
  }
  __syncthreads();
}

__global__ __launch_bounds__(256, 1) void tail_kernel(TailArgs ta) {
  const int tid = threadIdx.x, lane = tid & 63, w = tid >> 6;
  const int rl = lane & 15, qq = lane >> 4;
  __shared__ alignas(16) bf16 Plds[4 * 16 * 72];

  // ---- stage A: flash-attn partials, block = h*8 + chunk -------------------
  {
    const int h = blockIdx.x >> 3, c = blockIdx.x & 7;
    const bf16* qhp = ta.qh + (int64_t)(w * 16 + rl) * D_ + h * 64 + qq * 8;
    bf16x8 aq0 = *(const bf16x8*)(qhp);
    bf16x8 aq1 = *(const bf16x8*)(qhp + 32);
    float m_st[4], l_st[4];
    f32x4 acc_o[4] = {};
#pragma unroll
    for (int r = 0; r < 4; r++) { m_st[r] = -3.0e38f; l_st[r] = 0.f; }
    bf16* pl = Plds + w * 1152;
    const bf16* khb = ta.kh + (int64_t)(c * 1024) * D_ + h * 64 + qq * 8;
    const bf16* vtb = ta.vhT + (int64_t)(h * 64) * M_ + c * 1024 + qq * 8;
    for (int nt = 0; nt < 16; nt++) {
      int mb = nt * 64;
      bf16x8 bk0[4], bk1[4], vv0[4], vv1[4];
#pragma unroll
      for (int j = 0; j < 4; j++) {
        const bf16* p = khb + (int64_t)(mb + j * 16 + rl) * D_;
        bk0[j] = *(const bf16x8*)(p);
        bk1[j] = *(const bf16x8*)(p + 32);
        const bf16* q = vtb + (int64_t)(j * 16 + rl) * M_ + mb;
        vv0[j] = *(const bf16x8*)(q);
        vv1[j] = *(const bf16x8*)(q + 32);
      }
      f32x4 s[4] = {};
#pragma unroll
      for (int j = 0; j < 4; j++) {
        s[j] = mfma16(aq0, bk0[j], s[j]);
        s[j] = mfma16(aq1, bk1[j], s[j]);
      }
      float rmax[4], alpha[4], rsum[4];
#pragma unroll
      for (int r = 0; r < 4; r++)
        rmax[r] = fmaxf(fmaxf(s[0][r], s[1][r]), fmaxf(s[2][r], s[3][r]));
#pragma unroll
      for (int msk = 1; msk <= 8; msk <<= 1)
#pragma unroll
        for (int r = 0; r < 4; r++)
          rmax[r] = fmaxf(rmax[r], __shfl_xor(rmax[r], msk, 64));
#pragma unroll
      for (int r = 0; r < 4; r++) {
        float mn = fmaxf(m_st[r], rmax[r]);
        alpha[r] = __expf(m_st[r] - mn);
        m_st[r] = mn;
        rsum[r] = 0.f;
      }
#pragma unroll
      for (int j = 0; j < 4; j++)
#pragma unroll
        for (int r = 0; r < 4; r++) {
          float p = __expf(s[j][r] - m_st[r]);
          rsum[r] += p;
          pl[(qq * 4 + r) * 72 + j * 16 + rl] = (bf16)p;
        }
#pragma unroll
      for (int msk = 1; msk <= 8; msk <<= 1)
#pragma unroll
        for (int r = 0; r < 4; r++) rsum[r] += __shfl_xor(rsum[r], msk, 64);
#pragma unroll
      for (int r = 0; r < 4; r++) l_st[r] = l_st[r] * alpha[r] + rsum[r];
#pragma unroll
      for (int j = 0; j < 4; j++)
#pragma unroll
        for (int r = 0; r < 4; r++) acc_o[j][r] *= alpha[r];
      bf16x8 pa0 = *(const bf16x8*)(pl + rl * 72 + qq * 8);
      bf16x8 pa1 = *(const bf16x8*)(pl + rl * 72 + 32 + qq * 8);
#pragma unroll
      for (int j = 0; j < 4; j++) {
        acc_o[j] = mfma16(pa0, vv0[j], acc_o[j]);
        acc_o[j] = mfma16(pa1, vv1[j], acc_o[j]);
      }
    }
    float* op = ta.opart + (int64_t)(h * 8 + c) * 64 * 64;
#pragma unroll
    for (int j = 0; j < 4; j++)
#pragma unroll
      for (int r = 0; r < 4; r++)
        op[(w * 16 + qq * 4 + r) * 64 + j * 16 + rl] = acc_o[j][r];
    if (rl == 0) {
      float* mlp = ta.ml + (int64_t)(h * 8 + c) * 128;
#pragma unroll
      for (int r = 0; r < 4; r++) {
        mlp[w * 16 + qq * 4 + r] = m_st[r];
        mlp[64 + w * 16 + qq * 4 + r] = l_st[r];
      }
    }
  }
  grid_sync(ta.bar, 128 * 1);

  // ---- stage B: combine partials -> ctx -----------------------------------
  if (blockIdx.x < 16) {
    int h = blockIdx.x;
    int d = tid & 63;
    for (int b = tid >> 6; b < 64; b += 4) {
      float mv_[8], lv_[8], mstar = -3.0e38f;
#pragma unroll
      for (int c = 0; c < 8; c++) {
        mv_[c] = ta.ml[(int64_t)(h * 8 + c) * 128 + b];
        lv_[c] = ta.ml[(int64_t)(h * 8 + c) * 128 + 64 + b];
        mstar = fmaxf(mstar, mv_[c]);
      }
      float lsum = 0.f, osum = 0.f;
#pragma unroll
      for (int c = 0; c < 8; c++) {
        float f = __expf(mv_[c] - mstar);
        lsum += lv_[c] * f;
        osum += ta.opart[((int64_t)(h * 8 + c) * 64 + b) * 64 + d] * f;
      }
      ta.ctx[(int64_t)b * D_ + h * 64 + d] = (bf16)(osum / lsum);
    }
  }
  grid_sync(ta.bar, 128 * 2);

  // ---- stage C: ms = ctx @ outwb^T + outb -> xms[:, D:] -------------------
  if (blockIdx.x < 16) {
    int n0 = blockIdx.x * 64;
    thin_gemm<2, 0, 1024, bf16>(ta.ctx, D_, ta.outwb + (int64_t)n0 * D_, D_,
                                ta.xms + D_ + n0, 2 * D_, ta.outb + n0, 1.0f,
                                nullptr, 0);
  }
  grid_sync(ta.bar, 128 * 3);

  // ---- stage D: g1 = relu([x,ms] @ gW1^T + gb1) ---------------------------
  if (blockIdx.x < 16) {
    int n0 = blockIdx.x * 64;
    thin_gemm<2, 1, 2048, bf16>(ta.xms, 2 * D_, ta.gW1b + (int64_t)n0 * 2 * D_,
                                2 * D_, ta.g1 + n0, D_, ta.gb1 + n0, 1.0f,
                                nullptr, 0);
  }
  grid_sync(ta.bar, 128 * 4);

  // ---- stage E: gated = sigmoid(g1 @ gW2^T + gb2) * ms -> xgm[:, D:] ------
  if (blockIdx.x < 16) {
    int n0 = blockIdx.x * 64;
    thin_gemm<2, 2, 1024, bf16>(ta.g1, D_, ta.gW2b + (int64_t)n0 * D_, D_,
                                ta.xgm + D_ + n0, 2 * D_, ta.gb2 + n0, 1.0f,
                                ta.xms + D_ + n0, 2 * D_);
  }
  grid_sync(ta.bar, 128 * 5);

  // ---- stage F: h1 = relu([x,gated] @ iW1^T + ib1) ------------------------
  if (blockIdx.x < 32) {
    int n0 = blockIdx.x * 64;
    thin_gemm<2, 1, 2048, bf16>(ta.xgm, 2 * D_, ta.iW1b + (int64_t)n0 * 2 * D_,
                                2 * D_, ta.h1 + n0, 2 * D_, ta.ib1 + n0, 1.0f,
                                nullptr, 0);
  }
  grid_sync(ta.bar, 128 * 6);

  // ---- stage G: out = h1 @ iW2^T + ib2 (fp32) -----------------------------
  if (blockIdx.x < 16) {
    int n0 = blockIdx.x * 64;
    thin_gemm<2, 0, 2048, float>(ta.h1, 2 * D_, ta.iW2b + (int64_t)n0 * 2 * D_,
                                 2 * D_, ta.out + n0, D_, ta.ib2 + n0, 1.0f,
                                 nullptr, 0);
  }
}

// ------------------------------- launch ------------------------------------
extern "C" void kernel_launch(void* const* d_in, const int* in_sizes, int n_in,
                              void* d_out, int out_size, void* d_ws,
                              size_t ws_size, hipStream_t stream) {
  (void)in_sizes; (void)n_in; (void)out_size;
  const float* x    = (const float*)d_in[0];
  const float* mk   = (const float*)d_in[1];
  const float* mv   = (const float*)d_in[2];
  const float* Wq   = (const float*)d_in[3];
  const float* bq   = (const float*)d_in[4];
  const float* Wk   = (const float*)d_in[5];
  const float* bk   = (const float*)d_in[6];
  const float* Wv   = (const float*)d_in[7];
  const float* bv   = (const float*)d_in[8];
  const float* inw  = (const float*)d_in[9];
  const float* inb  = (const float*)d_in[10];
  const float* outw = (const float*)d_in[11];
  const float* outb = (const float*)d_in[12];
  const float* gW1  = (const float*)d_in[13];
  const float* gb1  = (const float*)d_in[14];
  const float* gW2  = (const float*)d_in[15];
  const float* gb2  = (const float*)d_in[16];
  const float* iW1  = (const float*)d_in[17];
  const float* ib1  = (const float*)d_in[18];
  const float* iW2  = (const float*)d_in[19];
  const float* ib2  = (const float*)d_in[20];

  char* ws = (char*)d_ws;
  size_t off = 0;
  auto alloc = [&](size_t bytes) {
    char* p = ws + off;
    off += (bytes + 255) & ~(size_t)255;
    return p;
  };
  bf16* mkmv  = (bf16*)alloc((size_t)2 * M_ * D_ * 2);
  bf16* inpj  = (bf16*)alloc((size_t)3 * D_ * D_ * 2);
  bf16* WT    = (bf16*)alloc((size_t)3 * D_ * D_ * 2);
  bf16* Wc    = (bf16*)alloc((size_t)3 * D_ * D_ * 2);
  float* bc   = (float*)alloc(3 * D_ * 4);
  bf16* xms   = (bf16*)alloc((size_t)B_ * 2 * D_ * 2);
  bf16* xgm   = (bf16*)alloc((size_t)B_ * 2 * D_ * 2);
  bf16* qh    = (bf16*)alloc((size_t)B_ * D_ * 2);
  bf16* kh    = (bf16*)alloc((size_t)M_ * D_ * 2);
  bf16* vhT   = (bf16*)alloc((size_t)M_ * D_ * 2);
  float* opart= (float*)alloc((size_t)H_ * 8 * 64 * 64 * 4);
  float* ml   = (float*)alloc((size_t)H_ * 8 * 128 * 4);
  bf16* ctx   = (bf16*)alloc((size_t)B_ * D_ * 2);
  bf16* g1    = (bf16*)alloc((size_t)B_ * D_ * 2);
  bf16* h1    = (bf16*)alloc((size_t)B_ * 2 * D_ * 2);
  bf16* gW1b  = (bf16*)alloc((size_t)D_ * 2 * D_ * 2);
  bf16* gW2b  = (bf16*)alloc((size_t)D_ * D_ * 2);
  bf16* iW1b  = (bf16*)alloc((size_t)2 * D_ * 2 * D_ * 2);
  bf16* iW2b  = (bf16*)alloc((size_t)D_ * 2 * D_ * 2);
  bf16* outwb = (bf16*)alloc((size_t)D_ * D_ * 2);
  unsigned* bar = (unsigned*)alloc(256);
  if (ws_size < off) return;

  hipMemsetAsync(bar, 0, 4, stream);

  // L1: prep
  PrepArgs pa;
  pa.d[0] = { mk,   mkmv,           2097152, 30, 0 };
  pa.d[1] = { mv,   mkmv + M_ * D_, 4194304, 30, 0 };
  pa.d[2] = { inw,  inpj,           4980736, 30, 0 };
  pa.d[3] = { gW1,  gW1b,           5505024, 30, 0 };
  pa.d[4] = { gW2,  gW2b,           5767168, 30, 0 };
  pa.d[5] = { iW1,  iW1b,           6815744, 30, 0 };
  pa.d[6] = { iW2,  iW2b,           7340032, 30, 0 };
  pa.d[7] = { outw, outwb,          7602176, 30, 0 };
  pa.d[8] = { x,    xms,            7618560, 10, 2 * D_ };
  pa.d[9] = { x,    xgm,            7634944, 10, 2 * D_ };
  pa.Wq = Wq; pa.Wk = Wk; pa.Wv = Wv; pa.inw = inw; pa.inb = inb;
  pa.bq = bq; pa.bk = bk; pa.bv = bv; pa.WT = WT; pa.bc = bc; pa.bar = bar;
  prep_kernel<<<dim3(33664), 256, 0, stream>>>(pa);

  // L2: Wc_z = Wi_z @ W_z (batched 1024^3)
  gemm_big<0><<<dim3(8, 8, 3), 256, 0, stream>>>(
      inpj, D_, (int64_t)D_ * D_, WT, D_, (int64_t)D_ * D_,
      Wc, D_, nullptr, nullptr, 0, D_, nullptr, nullptr, nullptr, nullptr);

  // L3: kh = mk @ Wck^T + bck ; vhT = (mv @ Wcv^T + bcv)^T ; + qh (16 blocks)
  gemm_big<1><<<dim3(1040), 256, 0, stream>>>(
      mkmv, D_, (int64_t)M_ * D_, Wc + (int64_t)D_ * D_, D_, (int64_t)D_ * D_,
      kh, D_, vhT, bc + D_, D_, D_,
      xms, Wc, qh, bc);

  // L4: fused tail
  TailArgs ta;
  ta.qh = qh; ta.kh = kh; ta.vhT = vhT; ta.opart = opart; ta.ml = ml;
  ta.ctx = ctx; ta.outwb = outwb; ta.gW1b = gW1b; ta.gW2b = gW2b;
  ta.iW1b = iW1b; ta.iW2b = iW2b; ta.outb = outb; ta.gb1 = gb1;
  ta.gb2 = gb2; ta.ib1 = ib1; ta.ib2 = ib2; ta.xms = xms; ta.xgm = xgm;
  ta.g1 = g1; ta.h1 = h1; ta.out = (float*)d_out; ta.bar = bar;
  tail_kernel<<<dim3(128), 256, 0, stream>>>(ta);
}

// Round 4
// 381.390 us; speedup vs baseline: 1.3853x; 1.3853x over previous
//
#include <hip/hip_runtime.h>
#include <hip/hip_bf16.h>
#include <stdint.h>

// ---------------------------------------------------------------------------
// AstrocyteMemoryModule r4: separate launches, every stage >=64 blocks.
//  L1  prep: converts + W^T + combined bias
//  L2  init: bias-broadcast into fp32 accum buffers (ms,g1,gate,h1,out)
//  L3  Wc = Wi@W (batched 1024^3)
//  L4  kh/vhT big GEMM (XCD swizzle, BK=64) + fused qh (16 thin blocks)
//  L5  flash attention partials  (256 blocks: 16 heads x 16 key-chunks)
//  L6  combine partials -> ctx   (64 blocks)
//  L7-L11 tail GEMM stages: split-N x split-K (64-256 blocks each),
//         fp32 atomicAdd into bias-pre-init buffers; the NEXT stage applies
//         the previous stage's nonlinearity while loading its A fragments.
// ---------------------------------------------------------------------------

typedef __bf16 bf16;
typedef __bf16 bf16x4 __attribute__((ext_vector_type(4)));
typedef __bf16 bf16x8 __attribute__((ext_vector_type(8)));
typedef float f32x4 __attribute__((ext_vector_type(4)));

#define D_ 1024
#define M_ 8192
#define B_ 64
#define H_ 16

static __device__ __forceinline__ void gload16(const void* g, void* l) {
  __builtin_amdgcn_global_load_lds(
      (const __attribute__((address_space(1))) void*)g,
      (__attribute__((address_space(3))) void*)l, 16, 0, 0);
}

static __device__ __forceinline__ f32x4 mfma16(bf16x8 a, bf16x8 b, f32x4 c) {
  return __builtin_amdgcn_mfma_f32_16x16x32_bf16(a, b, c, 0, 0, 0);
}

// ---------------- thin GEMM (M=64): C = A @ B^T, reg-prefetched -------------
template <int U, int KLEN, typename OutT>
__device__ __forceinline__ void thin_gemm(
    const bf16* __restrict__ A, int lda,
    const bf16* __restrict__ Bm, int ldb,
    OutT* __restrict__ C, int ldc,
    const float* __restrict__ bias, float scale) {
  const int tid = threadIdx.x, lane = tid & 63, w = tid >> 6;
  const int rl = lane & 15, qq = lane >> 4;
  const bf16* pa = A + (int64_t)(w * 16 + rl) * lda + qq * 8;
  const bf16* pb[4];
  pb[0] = Bm + (int64_t)rl * ldb + qq * 8;
  pb[1] = pb[0] + (int64_t)16 * ldb;
  pb[2] = pb[0] + (int64_t)32 * ldb;
  pb[3] = pb[0] + (int64_t)48 * ldb;
  f32x4 acc[4] = {};
  bf16x8 av[2][U], bv[2][U][4];
#pragma unroll
  for (int u = 0; u < U; u++) {
    av[0][u] = *(const bf16x8*)(pa + u * 32);
#pragma unroll
    for (int j = 0; j < 4; j++)
      bv[0][u][j] = *(const bf16x8*)(pb[j] + u * 32);
  }
  constexpr int NI = KLEN / (32 * U);
#pragma unroll
  for (int it = 0; it < NI; it++) {
    const int cur = it & 1, nxt = cur ^ 1;
    if (it + 1 < NI) {
      int k = (it + 1) * 32 * U;
#pragma unroll
      for (int u = 0; u < U; u++) {
        av[nxt][u] = *(const bf16x8*)(pa + k + u * 32);
#pragma unroll
        for (int j = 0; j < 4; j++)
          bv[nxt][u][j] = *(const bf16x8*)(pb[j] + k + u * 32);
      }
    }
#pragma unroll
    for (int u = 0; u < U; u++)
#pragma unroll
      for (int j = 0; j < 4; j++)
        acc[j] = mfma16(av[cur][u], bv[cur][u][j], acc[j]);
  }
#pragma unroll
  for (int j = 0; j < 4; j++) {
    int gn = j * 16 + rl;
    float bb = bias ? bias[gn] : 0.0f;
#pragma unroll
    for (int r = 0; r < 4; r++) {
      int gm = w * 16 + qq * 4 + r;
      C[(int64_t)gm * ldc + gn] = (OutT)((acc[j][r] + bb) * scale);
    }
  }
}

// ------------------------------ prep (L1) ----------------------------------
// blocks: [0,29760) converts, [29760,32832) W-transpose, [32832,33600) bias
struct CvtD { const float* src; bf16* dst; int end; };
struct PrepArgs {
  CvtD d[9];
  const float *Wq, *Wk, *Wv, *inw, *inb, *bq, *bk, *bv;
  bf16* WT;
  float* bc;
};

__global__ __launch_bounds__(256) void prep_kernel(PrepArgs a) {
  const int bx = blockIdx.x, tid = threadIdx.x;
  if (bx < 29760) {
    int g = bx * 256 + tid;
    CvtD dd = a.d[8];
    int begin = a.d[7].end;
#pragma unroll
    for (int t = 7; t >= 0; t--)
      if (g < a.d[t].end) { dd = a.d[t]; begin = t ? a.d[t - 1].end : 0; }
    int i = (g - begin) * 4;
    float4 v = *(const float4*)(dd.src + i);
    bf16x4 o = { (bf16)v.x, (bf16)v.y, (bf16)v.z, (bf16)v.w };
    *(bf16x4*)(dd.dst + i) = o;
  } else if (bx < 32832) {
    int t = bx - 29760;
    int z = t >> 10, rem = t & 1023;
    const float* src = z == 0 ? a.Wq : z == 1 ? a.Wk : a.Wv;
    bf16* out = a.WT + (int64_t)z * D_ * D_;
    __shared__ bf16 tile[32][33];
    int tx = tid & 31, ty = tid >> 5;
    int r0 = (rem >> 5) * 32, c0 = (rem & 31) * 32;
#pragma unroll
    for (int i = 0; i < 32; i += 8)
      tile[ty + i][tx] = (bf16)src[(int64_t)(r0 + ty + i) * D_ + c0 + tx];
    __syncthreads();
#pragma unroll
    for (int i = 0; i < 32; i += 8)
      out[(int64_t)(c0 + ty + i) * D_ + r0 + tx] = tile[tx][ty + i];
  } else {
    int t = bx - 32832;
    int w = tid >> 6, lane = tid & 63;
    int ng = t * 4 + w;  // [0, 3072)
    int z = ng >> 10;
    const float* Wi = a.inw + (int64_t)ng * D_;
    const float* b = z == 0 ? a.bq : z == 1 ? a.bk : a.bv;
    float acc = 0.f;
#pragma unroll
    for (int l = 0; l < D_; l += 64) acc += Wi[l + lane] * b[l + lane];
#pragma unroll
    for (int m = 32; m; m >>= 1) acc += __shfl_xor(acc, m, 64);
    if (lane == 0) a.bc[ng] = acc + a.inb[ng];
  }
}

// --------------------------- init accumulators (L2) ------------------------
__global__ __launch_bounds__(256) void init_bias(
    const float* __restrict__ outb, const float* __restrict__ gb1,
    const float* __restrict__ gb2, const float* __restrict__ ib1,
    const float* __restrict__ ib2, float* __restrict__ msR,
    float* __restrict__ g1R, float* __restrict__ gateR,
    float* __restrict__ h1R, float* __restrict__ out) {
  int c = (blockIdx.x * 256 + threadIdx.x) * 4;  // [0, 6144)
  int row = blockIdx.y;
  const float* b; float* dst; int n;
  if (c < 1024)      { b = outb; dst = msR   + row * 1024; n = c; }
  else if (c < 2048) { b = gb1;  dst = g1R   + row * 1024; n = c - 1024; }
  else if (c < 3072) { b = gb2;  dst = gateR + row * 1024; n = c - 2048; }
  else if (c < 5120) { b = ib1;  dst = h1R   + row * 2048; n = c - 3072; }
  else               { b = ib2;  dst = out   + row * 1024; n = c - 5120; }
  *(float4*)(dst + n) = *(const float4*)(b + n);
}

// ------------------------- big GEMM: C = A @ B^T (BK=64) -------------------
template <int MODE>
__global__ __launch_bounds__(256) void gemm_big(
    const bf16* __restrict__ A, int lda, int64_t sA,
    const bf16* __restrict__ Bm, int ldb, int64_t sB,
    bf16* __restrict__ C, int ldc, bf16* __restrict__ Ct,
    const float* __restrict__ bias, int64_t sbias, int K,
    const bf16* __restrict__ qA, const bf16* __restrict__ qB,
    bf16* __restrict__ qC, const float* __restrict__ qbias) {
  int m0, n0, z;
  if (MODE == 0) {
    z = blockIdx.z; m0 = blockIdx.y * 128; n0 = blockIdx.x * 128;
  } else {
    if ((int)blockIdx.x >= 1024) {  // fused qh: 16 thin blocks
      int n0q = ((int)blockIdx.x - 1024) * 64;
      thin_gemm<2, 1024, bf16>(qA, D_, qB + (int64_t)n0q * D_, D_,
                               qC + n0q, D_, qbias + n0q, 0.125f);
      return;
    }
    int lin = blockIdx.x, xcd = lin & 7, slot = lin >> 3;
    z = slot >> 6;
    int r = slot & 63;
    m0 = (xcd * 8 + (r >> 3)) * 128;
    n0 = (r & 7) * 128;
  }
  A += (int64_t)z * sA; Bm += (int64_t)z * sB;
  if (bias) bias += (int64_t)z * sbias;
  __shared__ alignas(16) bf16 As[128 * 64];
  __shared__ alignas(16) bf16 Bs[128 * 64];
  const int tid = threadIdx.x, lane = tid & 63, w = tid >> 6;
  const int wm = (w & 1) * 64, wn = (w >> 1) * 64;
  const int rl = lane & 15, qq = lane >> 4;
  f32x4 acc[4][4] = {};

  const bf16 *gA[4], *gB[4];
  bf16 *lA[4], *lB[4];
#pragma unroll
  for (int it = 0; it < 4; it++) {
    int cc = it * 256 + w * 64 + lane;
    int r = cc >> 3, qp = cc & 7, q = qp ^ (r & 7);
    gA[it] = A + (int64_t)(m0 + r) * lda + q * 8;
    gB[it] = Bm + (int64_t)(n0 + r) * ldb + q * 8;
    lA[it] = As + (it * 256 + w * 64) * 8;
    lB[it] = Bs + (it * 256 + w * 64) * 8;
  }
  for (int k0 = 0; k0 < K; k0 += 64) {
    __syncthreads();
#pragma unroll
    for (int it = 0; it < 4; it++) {
      gload16(gA[it] + k0, lA[it]);
      gload16(gB[it] + k0, lB[it]);
    }
    __syncthreads();
#pragma unroll
    for (int kk = 0; kk < 2; kk++) {
      bf16x8 af[4], bb[4];
#pragma unroll
      for (int i = 0; i < 4; i++) {
        int ar = wm + i * 16 + rl;
        af[i] = *(const bf16x8*)(As + ar * 64 + (((kk * 4 + qq) ^ (ar & 7)) * 8));
      }
#pragma unroll
      for (int j = 0; j < 4; j++) {
        int br = wn + j * 16 + rl;
        bb[j] = *(const bf16x8*)(Bs + br * 64 + (((kk * 4 + qq) ^ (br & 7)) * 8));
      }
#pragma unroll
      for (int i = 0; i < 4; i++)
#pragma unroll
        for (int j = 0; j < 4; j++)
          acc[i][j] = mfma16(af[i], bb[j], acc[i][j]);
    }
  }
  if (MODE == 1 && z == 1) {
#pragma unroll
    for (int j = 0; j < 4; j++) {
      int gn = n0 + wn + j * 16 + rl;
      float bb = bias ? bias[gn] : 0.0f;
#pragma unroll
      for (int i = 0; i < 4; i++) {
        int gm0 = m0 + wm + i * 16 + qq * 4;
        f32x4 a = acc[i][j];
        bf16x4 o = { (bf16)(a[0] + bb), (bf16)(a[1] + bb),
                     (bf16)(a[2] + bb), (bf16)(a[3] + bb) };
        *(bf16x4*)(Ct + (int64_t)gn * M_ + gm0) = o;
      }
    }
  } else {
#pragma unroll
    for (int j = 0; j < 4; j++) {
      int gn = n0 + wn + j * 16 + rl;
      float bb = bias ? bias[gn] : 0.0f;
#pragma unroll
      for (int i = 0; i < 4; i++) {
        int gm0 = m0 + wm + i * 16 + qq * 4;
#pragma unroll
        for (int r = 0; r < 4; r++)
          C[(int64_t)(gm0 + r) * ldc + gn] = (bf16)(acc[i][j][r] + bb);
      }
    }
  }
}

// --------------------------- flash attention (L5) --------------------------
// 256 blocks: h (16) x key-chunk c (16, 512 keys each)
__global__ __launch_bounds__(256) void flash_kernel(
    const bf16* __restrict__ qh, const bf16* __restrict__ kh,
    const bf16* __restrict__ vhT, float* __restrict__ opart,
    float* __restrict__ ml) {
  const int tid = threadIdx.x, lane = tid & 63, w = tid >> 6;
  const int rl = lane & 15, qq = lane >> 4;
  const int h = blockIdx.x >> 4, c = blockIdx.x & 15;
  __shared__ alignas(16) bf16 Plds[4 * 16 * 72];
  const bf16* qhp = qh + (int64_t)(w * 16 + rl) * D_ + h * 64 + qq * 8;
  bf16x8 aq0 = *(const bf16x8*)(qhp);
  bf16x8 aq1 = *(const bf16x8*)(qhp + 32);
  float m_st[4], l_st[4];
  f32x4 acc_o[4] = {};
#pragma unroll
  for (int r = 0; r < 4; r++) { m_st[r] = -3.0e38f; l_st[r] = 0.f; }
  bf16* pl = Plds + w * 1152;
  const bf16* khb = kh + (int64_t)(c * 512) * D_ + h * 64 + qq * 8;
  const bf16* vtb = vhT + (int64_t)(h * 64) * M_ + c * 512 + qq * 8;
  for (int nt = 0; nt < 8; nt++) {
    int mb = nt * 64;
    bf16x8 bk0[4], bk1[4];
#pragma unroll
    for (int j = 0; j < 4; j++) {
      const bf16* p = khb + (int64_t)(mb + j * 16 + rl) * D_;
      bk0[j] = *(const bf16x8*)(p);
      bk1[j] = *(const bf16x8*)(p + 32);
    }
    f32x4 s[4] = {};
#pragma unroll
    for (int j = 0; j < 4; j++) {
      s[j] = mfma16(aq0, bk0[j], s[j]);
      s[j] = mfma16(aq1, bk1[j], s[j]);
    }
    float rmax[4], alpha[4], rsum[4];
#pragma unroll
    for (int r = 0; r < 4; r++)
      rmax[r] = fmaxf(fmaxf(s[0][r], s[1][r]), fmaxf(s[2][r], s[3][r]));
#pragma unroll
    for (int msk = 1; msk <= 8; msk <<= 1)
#pragma unroll
      for (int r = 0; r < 4; r++)
        rmax[r] = fmaxf(rmax[r], __shfl_xor(rmax[r], msk, 64));
#pragma unroll
    for (int r = 0; r < 4; r++) {
      float mn = fmaxf(m_st[r], rmax[r]);
      alpha[r] = __expf(m_st[r] - mn);
      m_st[r] = mn;
      rsum[r] = 0.f;
    }
#pragma unroll
    for (int j = 0; j < 4; j++)
#pragma unroll
      for (int r = 0; r < 4; r++) {
        float p = __expf(s[j][r] - m_st[r]);
        rsum[r] += p;
        pl[(qq * 4 + r) * 72 + j * 16 + rl] = (bf16)p;
      }
#pragma unroll
    for (int msk = 1; msk <= 8; msk <<= 1)
#pragma unroll
      for (int r = 0; r < 4; r++) rsum[r] += __shfl_xor(rsum[r], msk, 64);
#pragma unroll
    for (int r = 0; r < 4; r++) l_st[r] = l_st[r] * alpha[r] + rsum[r];
#pragma unroll
    for (int j = 0; j < 4; j++)
#pragma unroll
      for (int r = 0; r < 4; r++) acc_o[j][r] *= alpha[r];
    bf16x8 pa0 = *(const bf16x8*)(pl + rl * 72 + qq * 8);
    bf16x8 pa1 = *(const bf16x8*)(pl + rl * 72 + 32 + qq * 8);
#pragma unroll
    for (int j = 0; j < 4; j++) {
      const bf16* q = vtb + (int64_t)(j * 16 + rl) * M_ + mb;
      bf16x8 v0 = *(const bf16x8*)(q);
      bf16x8 v1 = *(const bf16x8*)(q + 32);
      acc_o[j] = mfma16(pa0, v0, acc_o[j]);
      acc_o[j] = mfma16(pa1, v1, acc_o[j]);
    }
  }
  float* op = opart + (int64_t)(h * 16 + c) * 64 * 64;
#pragma unroll
  for (int j = 0; j < 4; j++)
#pragma unroll
    for (int r = 0; r < 4; r++)
      op[(w * 16 + qq * 4 + r) * 64 + j * 16 + rl] = acc_o[j][r];
  if (rl == 0) {
    float* mlp = ml + (int64_t)(h * 16 + c) * 128;
#pragma unroll
    for (int r = 0; r < 4; r++) {
      mlp[w * 16 + qq * 4 + r] = m_st[r];
      mlp[64 + w * 16 + qq * 4 + r] = l_st[r];
    }
  }
}

// --------------------------- combine -> ctx (L6) ---------------------------
__global__ __launch_bounds__(256) void combine_kernel(
    const float* __restrict__ opart, const float* __restrict__ ml,
    bf16* __restrict__ ctx) {
  const int h = blockIdx.x >> 2, g = blockIdx.x & 3;
  const int d = threadIdx.x & 63;
#pragma unroll
  for (int it = 0; it < 4; it++) {
    int b = g * 16 + (threadIdx.x >> 6) + it * 4;
    float mstar = -3.0e38f;
    float mv_[16], lv_[16];
#pragma unroll
    for (int cc = 0; cc < 16; cc++) {
      mv_[cc] = ml[(int64_t)(h * 16 + cc) * 128 + b];
      lv_[cc] = ml[(int64_t)(h * 16 + cc) * 128 + 64 + b];
      mstar = fmaxf(mstar, mv_[cc]);
    }
    float lsum = 0.f, osum = 0.f;
#pragma unroll
    for (int cc = 0; cc < 16; cc++) {
      float f = __expf(mv_[cc] - mstar);
      lsum += lv_[cc] * f;
      osum += opart[((int64_t)(h * 16 + cc) * 64 + b) * 64 + d] * f;
    }
    ctx[(int64_t)b * D_ + h * 64 + d] = (bf16)(osum / lsum);
  }
}

// ----------------------- tail GEMM stage (L7..L11) -------------------------
// C(raw fp32, bias-pre-init) += A_chunk @ B_chunk^T via atomicAdd.
// Chunk kinds: 0 = bf16 plain; 1 = fp32 plain; 2 = relu(fp32);
//              3 = sigmoid(p0)*p1 (both fp32).
struct Chunk { const void* p0; const void* p1; int ld; int kind; };
struct StageArgs { Chunk c[8]; };

__global__ __launch_bounds__(256) void tail_stage(
    StageArgs sa, const bf16* __restrict__ Bw, int ldb,
    float* __restrict__ Craw, int ldc) {
  const int n0 = blockIdx.x * 64, kc = blockIdx.y;
  const Chunk ch = sa.c[kc];
  const int tid = threadIdx.x, lane = tid & 63, w = tid >> 6;
  const int rl = lane & 15, qq = lane >> 4;
  const int m = w * 16 + rl;
  const bf16* pb[4];
#pragma unroll
  for (int j = 0; j < 4; j++)
    pb[j] = Bw + (int64_t)(n0 + j * 16 + rl) * ldb + kc * 256 + qq * 8;
  f32x4 acc[4] = {};
#pragma unroll
  for (int kk = 0; kk < 8; kk++) {
    bf16x8 af;
    if (ch.kind == 0) {
      af = *(const bf16x8*)((const bf16*)ch.p0 + (int64_t)m * ch.ld +
                            kk * 32 + qq * 8);
    } else {
      const float* p = (const float*)ch.p0 + (int64_t)m * ch.ld + kk * 32 + qq * 8;
      float4 u0 = *(const float4*)p;
      float4 u1 = *(const float4*)(p + 4);
      if (ch.kind == 2) {
        u0.x = fmaxf(u0.x, 0.f); u0.y = fmaxf(u0.y, 0.f);
        u0.z = fmaxf(u0.z, 0.f); u0.w = fmaxf(u0.w, 0.f);
        u1.x = fmaxf(u1.x, 0.f); u1.y = fmaxf(u1.y, 0.f);
        u1.z = fmaxf(u1.z, 0.f); u1.w = fmaxf(u1.w, 0.f);
      } else if (ch.kind == 3) {
        const float* pm = (const float*)ch.p1 + (int64_t)m * ch.ld + kk * 32 + qq * 8;
        float4 m0 = *(const float4*)pm;
        float4 m1 = *(const float4*)(pm + 4);
        u0.x = m0.x / (1.f + __expf(-u0.x)); u0.y = m0.y / (1.f + __expf(-u0.y));
        u0.z = m0.z / (1.f + __expf(-u0.z)); u0.w = m0.w / (1.f + __expf(-u0.w));
        u1.x = m1.x / (1.f + __expf(-u1.x)); u1.y = m1.y / (1.f + __expf(-u1.y));
        u1.z = m1.z / (1.f + __expf(-u1.z)); u1.w = m1.w / (1.f + __expf(-u1.w));
      }
      af = (bf16x8){ (bf16)u0.x, (bf16)u0.y, (bf16)u0.z, (bf16)u0.w,
                     (bf16)u1.x, (bf16)u1.y, (bf16)u1.z, (bf16)u1.w };
    }
    bf16x8 bf_[4];
#pragma unroll
    for (int j = 0; j < 4; j++) bf_[j] = *(const bf16x8*)(pb[j] + kk * 32);
#pragma unroll
    for (int j = 0; j < 4; j++) acc[j] = mfma16(af, bf_[j], acc[j]);
  }
#pragma unroll
  for (int j = 0; j < 4; j++) {
    int gn = n0 + j * 16 + rl;
#pragma unroll
    for (int r = 0; r < 4; r++) {
      int gm = w * 16 + qq * 4 + r;
      atomicAdd(&Craw[(int64_t)gm * ldc + gn], acc[j][r]);
    }
  }
}

// ------------------------------- launch ------------------------------------
extern "C" void kernel_launch(void* const* d_in, const int* in_sizes, int n_in,
                              void* d_out, int out_size, void* d_ws,
                              size_t ws_size, hipStream_t stream) {
  (void)in_sizes; (void)n_in; (void)out_size;
  const float* x    = (const float*)d_in[0];
  const float* mk   = (const float*)d_in[1];
  const float* mv   = (const float*)d_in[2];
  const float* Wq   = (const float*)d_in[3];
  const float* bq   = (const float*)d_in[4];
  const float* Wk   = (const float*)d_in[5];
  const float* bk   = (const float*)d_in[6];
  const float* Wv   = (const float*)d_in[7];
  const float* bv   = (const float*)d_in[8];
  const float* inw  = (const float*)d_in[9];
  const float* inb  = (const float*)d_in[10];
  const float* outw = (const float*)d_in[11];
  const float* outb = (const float*)d_in[12];
  const float* gW1  = (const float*)d_in[13];
  const float* gb1  = (const float*)d_in[14];
  const float* gW2  = (const float*)d_in[15];
  const float* gb2  = (const float*)d_in[16];
  const float* iW1  = (const float*)d_in[17];
  const float* ib1  = (const float*)d_in[18];
  const float* iW2  = (const float*)d_in[19];
  const float* ib2  = (const float*)d_in[20];

  char* ws = (char*)d_ws;
  size_t off = 0;
  auto alloc = [&](size_t bytes) {
    char* p = ws + off;
    off += (bytes + 255) & ~(size_t)255;
    return p;
  };
  bf16* mkmv  = (bf16*)alloc((size_t)2 * M_ * D_ * 2);
  bf16* inpj  = (bf16*)alloc((size_t)3 * D_ * D_ * 2);
  bf16* WT    = (bf16*)alloc((size_t)3 * D_ * D_ * 2);
  bf16* Wc    = (bf16*)alloc((size_t)3 * D_ * D_ * 2);
  float* bc   = (float*)alloc(3 * D_ * 4);
  bf16* xbf   = (bf16*)alloc((size_t)B_ * D_ * 2);
  bf16* qh    = (bf16*)alloc((size_t)B_ * D_ * 2);
  bf16* kh    = (bf16*)alloc((size_t)M_ * D_ * 2);
  bf16* vhT   = (bf16*)alloc((size_t)M_ * D_ * 2);
  float* opart= (float*)alloc((size_t)H_ * 16 * 64 * 64 * 4);
  float* ml   = (float*)alloc((size_t)H_ * 16 * 128 * 4);
  bf16* ctx   = (bf16*)alloc((size_t)B_ * D_ * 2);
  float* msR  = (float*)alloc((size_t)B_ * D_ * 4);
  float* g1R  = (float*)alloc((size_t)B_ * D_ * 4);
  float* gateR= (float*)alloc((size_t)B_ * D_ * 4);
  float* h1R  = (float*)alloc((size_t)B_ * 2 * D_ * 4);
  bf16* gW1b  = (bf16*)alloc((size_t)D_ * 2 * D_ * 2);
  bf16* gW2b  = (bf16*)alloc((size_t)D_ * D_ * 2);
  bf16* iW1b  = (bf16*)alloc((size_t)2 * D_ * 2 * D_ * 2);
  bf16* iW2b  = (bf16*)alloc((size_t)D_ * 2 * D_ * 2);
  bf16* outwb = (bf16*)alloc((size_t)D_ * D_ * 2);
  if (ws_size < off) return;

  // L1: prep
  PrepArgs pa;
  pa.d[0] = { mk,   mkmv,           2097152 };
  pa.d[1] = { mv,   mkmv + M_ * D_, 4194304 };
  pa.d[2] = { inw,  inpj,           4980736 };
  pa.d[3] = { gW1,  gW1b,           5505024 };
  pa.d[4] = { gW2,  gW2b,           5767168 };
  pa.d[5] = { iW1,  iW1b,           6815744 };
  pa.d[6] = { iW2,  iW2b,           7340032 };
  pa.d[7] = { outw, outwb,          7602176 };
  pa.d[8] = { x,    xbf,            7618560 };
  pa.Wq = Wq; pa.Wk = Wk; pa.Wv = Wv; pa.inw = inw; pa.inb = inb;
  pa.bq = bq; pa.bk = bk; pa.bv = bv; pa.WT = WT; pa.bc = bc;
  prep_kernel<<<dim3(33600), 256, 0, stream>>>(pa);

  // L2: bias-init fp32 accumulators (incl. d_out)
  init_bias<<<dim3(6, 64), 256, 0, stream>>>(outb, gb1, gb2, ib1, ib2,
                                             msR, g1R, gateR, h1R,
                                             (float*)d_out);

  // L3: Wc_z = Wi_z @ W_z
  gemm_big<0><<<dim3(8, 8, 3), 256, 0, stream>>>(
      inpj, D_, (int64_t)D_ * D_, WT, D_, (int64_t)D_ * D_,
      Wc, D_, nullptr, nullptr, 0, D_, nullptr, nullptr, nullptr, nullptr);

  // L4: kh / vhT (+ fused qh)
  gemm_big<1><<<dim3(1040), 256, 0, stream>>>(
      mkmv, D_, (int64_t)M_ * D_, Wc + (int64_t)D_ * D_, D_, (int64_t)D_ * D_,
      kh, D_, vhT, bc + D_, D_, D_,
      xbf, Wc, qh, bc);

  // L5: flash partials ; L6: combine -> ctx
  flash_kernel<<<dim3(256), 256, 0, stream>>>(qh, kh, vhT, opart, ml);
  combine_kernel<<<dim3(64), 256, 0, stream>>>(opart, ml, ctx);

  // L7: msR += ctx @ outwb^T          grid (16 n-tiles, 4 k-chunks)
  StageArgs s7;
  for (int kc = 0; kc < 4; kc++) s7.c[kc] = { ctx + kc * 256, nullptr, D_, 0 };
  tail_stage<<<dim3(16, 4), 256, 0, stream>>>(s7, outwb, D_, msR, D_);

  // L8: g1R += [x | ms] @ gW1^T       grid (16, 8)
  StageArgs s8;
  for (int kc = 0; kc < 4; kc++) s8.c[kc] = { xbf + kc * 256, nullptr, D_, 0 };
  for (int kc = 4; kc < 8; kc++) s8.c[kc] = { msR + (kc - 4) * 256, nullptr, D_, 1 };
  tail_stage<<<dim3(16, 8), 256, 0, stream>>>(s8, gW1b, 2 * D_, g1R, D_);

  // L9: gateR += relu(g1R) @ gW2^T    grid (16, 4)
  StageArgs s9;
  for (int kc = 0; kc < 4; kc++) s9.c[kc] = { g1R + kc * 256, nullptr, D_, 2 };
  tail_stage<<<dim3(16, 4), 256, 0, stream>>>(s9, gW2b, D_, gateR, D_);

  // L10: h1R += [x | sigmoid(gateR)*msR] @ iW1^T   grid (32, 8)
  StageArgs s10;
  for (int kc = 0; kc < 4; kc++) s10.c[kc] = { xbf + kc * 256, nullptr, D_, 0 };
  for (int kc = 4; kc < 8; kc++)
    s10.c[kc] = { gateR + (kc - 4) * 256, msR + (kc - 4) * 256, D_, 3 };
  tail_stage<<<dim3(32, 8), 256, 0, stream>>>(s10, iW1b, 2 * D_, h1R, 2 * D_);

  // L11: out += relu(h1R) @ iW2^T     grid (16, 8)
  StageArgs s11;
  for (int kc = 0; kc < 8; kc++) s11.c[kc] = { h1R + kc * 256, nullptr, 2 * D_, 2 };
  tail_stage<<<dim3(16, 8), 256, 0, stream>>>(s11, iW2b, 2 * D_,
                                              (float*)d_out, D_);
}